// Round 2
// baseline (568.331 us; speedup 1.0000x reference)
//
#include <hip/hip_runtime.h>
#include <hip/hip_bf16.h>
#include <stdint.h>

typedef __bf16 bf16_t;
typedef __bf16 bf16x8 __attribute__((ext_vector_type(8)));
typedef __bf16 bf16x4 __attribute__((ext_vector_type(4)));
typedef float f32x4 __attribute__((ext_vector_type(4)));

template <int V> struct ic { static constexpr int value = V; };

// async global->LDS, 16B per lane. LDS dest must be wave-uniform base + lane*16.
__device__ __forceinline__ void gload_lds16(const bf16_t* g, bf16_t* l) {
  __builtin_amdgcn_global_load_lds((const __attribute__((address_space(1))) void*)g,
                                   (__attribute__((address_space(3))) void*)l, 16, 0, 0);
}

// ---------------- fp32 W[k][m] -> bf16 Bt[m][k] (tiled transpose + cast) --------
__global__ __launch_bounds__(256) void transpose_cast_k(const float* __restrict__ W,
                                                        bf16_t* __restrict__ Bt,
                                                        int KDin, int MDin) {
  __shared__ float tile[64][65];
  const int bm = blockIdx.x, bk = blockIdx.y;
  const int c = threadIdx.x & 63, r0 = threadIdx.x >> 6;
#pragma unroll
  for (int rr = 0; rr < 16; ++rr) {
    int row = rr * 4 + r0;
    tile[row][c] = W[(size_t)(bk * 64 + row) * MDin + bm * 64 + c];
  }
  __syncthreads();
#pragma unroll
  for (int rr = 0; rr < 16; ++rr) {
    int mo = rr * 4 + r0;
    Bt[(size_t)(bm * 64 + mo) * KDin + bk * 64 + c] = (bf16_t)tile[c][mo];
  }
}

// ---------------- feat[order[j]] -> bf16 featp[j]; also emit posf[j][3] --------
__global__ __launch_bounds__(256) void gather_cast_k(const float* __restrict__ feat,
                                                     const int* __restrict__ order,
                                                     const int* __restrict__ grid_coord,
                                                     bf16_t* __restrict__ featp,
                                                     float* __restrict__ posf) {
  const int id = blockIdx.x * 256 + threadIdx.x;  // 32768*192 total
  const int j = id / 192;
  const int c = (id % 192) * 4;
  const int g = order[j];
  const float4 v = *(const float4*)(feat + (size_t)g * 768 + c);
  bf16x4 o;
  o[0] = (bf16_t)v.x; o[1] = (bf16_t)v.y; o[2] = (bf16_t)v.z; o[3] = (bf16_t)v.w;
  *(bf16x4*)(featp + (size_t)j * 768 + c) = o;
  if (c == 0) {
    posf[j * 3 + 0] = (float)grid_coord[g * 3 + 0];
    posf[j * 3 + 1] = (float)grid_coord[g * 3 + 1];
    posf[j * 3 + 2] = (float)grid_coord[g * 3 + 2];
  }
}

// ---------------- persistent 128x256 ring-pipelined GEMM -----------------------
// C[j][m] = A[j][:].Bt[m][:] + bias.  A [32768][768] bf16, Bt [NT*256][768] bf16.
// Grid = 256 blocks (1/CU: 96KB LDS), 512 thr (8 waves, 2Mx4N -> 64x64/wave).
// Block b owns A-panel rows [b*128, b*128+128) and sweeps NT column tiles
// (bx = 0..NT-1), K = 768 = 24 K-tiles of BK=32, ONE phase per K-tile:
//   { ds_read af[4]/bf[4] from ring slot t&3 | stage K-tile t+3 into slot
//     (t+3)&3 | vmcnt(6) | barrier | lgkmcnt(0)+sched_barrier | 16 MFMA
//     (setprio 1) | barrier }
// Since 24 % 4 == 0, phases 21..23 of tile i stage NEXT tile's K-tiles 0..2
// into exactly the slots tile i+1's phases 0..2 read -> the ring never drains
// across tiles; pipeline fill happens once per block, and each tile's epilogue
// (RoPE / stores) overlaps the next tile's prefetch latency.  vmcnt(6) steady
// (3 loads/thread/K-tile, 3 K-tiles in flight); drain 3->0 only at block end.
// LDS XOR swizzle: 16B-unit o = r*4+phys, phys = slot ^ ((r>>1)&3), applied on
// the global source (linear gload_lds dest) and on the ds_read side.
// MODE 0: bf16 stores to Cq/Ck/Cv with fused RoPE on Q,K.  MODE 1: fp32
// scatter Cf[order[j]][:].
template <int MODE, int NT>
__global__ __launch_bounds__(512, 2) void gemm128_k(const bf16_t* __restrict__ A,
                                                    const bf16_t* __restrict__ Bt,
                                                    const float* __restrict__ bias,
                                                    bf16_t* __restrict__ Cq,
                                                    bf16_t* __restrict__ Ck,
                                                    bf16_t* __restrict__ Cv,
                                                    float* __restrict__ Cf,
                                                    const int* __restrict__ order,
                                                    const float* __restrict__ posf) {
  extern __shared__ bf16_t sm[];
  bf16_t* ldsA = sm;            // 4 slots x 4096 bf16 (8KB)  = 32KB
  bf16_t* ldsB = sm + 16384;    // 4 slots x 8192 bf16 (16KB) = 64KB

  const int tid = threadIdx.x;
  const int lane = tid & 63, wave = tid >> 6;
  const int wr = wave >> 2, wc = wave & 3;  // 2 x 4 wave grid
  const int lq = lane & 15, lk = lane >> 4;
  const int by = blockIdx.x;

  // staging geometry: unit o = r*4 + phys, phys = logical_slot ^ ((r>>1)&3)
  const int oA = tid;                       // A: 512 units (128 rows x 4)
  const int rA = oA >> 2, lsA = (oA & 3) ^ ((rA >> 1) & 3);
  const int oB0 = tid, oB1 = tid + 512;     // B: 1024 units (256 rows x 4)
  const int rB0 = oB0 >> 2, lsB0 = (oB0 & 3) ^ ((rB0 >> 1) & 3);
  const int rB1 = oB1 >> 2, lsB1 = (oB1 & 3) ^ ((rB1 >> 1) & 3);

  const bf16_t* pA = A + (size_t)(by * 128 + rA) * 768 + lsA * 8;
  const bf16_t* pB0 = Bt + (size_t)rB0 * 768 + lsB0 * 8;   // bx=0; advance per tile
  const bf16_t* pB1 = Bt + (size_t)rB1 * 768 + lsB1 * 8;

  auto stage = [&](const bf16_t* sB0, const bf16_t* sB1, int kt, int slot) {
    bf16_t* dA = ldsA + (slot << 12);
    bf16_t* dB = ldsB + (slot << 13);
    gload_lds16(pA + kt * 32, dA + oA * 8);
    gload_lds16(sB0 + kt * 32, dB + oB0 * 8);
    gload_lds16(sB1 + kt * 32, dB + oB1 * 8);
  };

  // ds_read slot for this lane (row = 16-aligned + lq -> (row>>1)&3 = (lq>>1)&3)
  const int pslot = lk ^ ((lq >> 1) & 3);

  f32x4 acc[4][4];

  auto ph = [&](int t, const bf16_t* sB0, const bf16_t* sB1, int skt,
                auto VMC, auto STGC) {
    constexpr int VM = decltype(VMC)::value;
    constexpr bool STG = decltype(STGC)::value;
    const bf16_t* Ab = ldsA + ((t & 3) << 12);
    const bf16_t* Bb = ldsB + ((t & 3) << 13);
    bf16x8 af[4], bfr[4];
#pragma unroll
    for (int m = 0; m < 4; ++m)
      af[m] = *(const bf16x8*)(Ab + (wr * 64 + m * 16 + lq) * 32 + pslot * 8);
#pragma unroll
    for (int n = 0; n < 4; ++n)
      bfr[n] = *(const bf16x8*)(Bb + (wc * 64 + n * 16 + lq) * 32 + pslot * 8);
    if constexpr (STG) stage(sB0, sB1, skt, (t + 3) & 3);
    if constexpr (VM == 6) asm volatile("s_waitcnt vmcnt(6)" ::: "memory");
    else if constexpr (VM == 3) asm volatile("s_waitcnt vmcnt(3)" ::: "memory");
    else if constexpr (VM == 0) asm volatile("s_waitcnt vmcnt(0)" ::: "memory");
    __builtin_amdgcn_s_barrier();
    asm volatile("s_waitcnt lgkmcnt(0)" ::: "memory");
    __builtin_amdgcn_sched_barrier(0);
    __builtin_amdgcn_s_setprio(1);
#pragma unroll
    for (int n = 0; n < 4; ++n)
#pragma unroll
      for (int m = 0; m < 4; ++m)
        acc[m][n] = __builtin_amdgcn_mfma_f32_16x16x32_bf16(af[m], bfr[n], acc[m][n], 0, 0, 0);
    __builtin_amdgcn_s_setprio(0);
    __builtin_amdgcn_s_barrier();
    __builtin_amdgcn_sched_barrier(0);
  };

  // ---- prologue: fill ring with K-tiles 0..2 of tile 0 (once per block)
  stage(pB0, pB1, 0, 0);
  stage(pB0, pB1, 1, 1);
  stage(pB0, pB1, 2, 2);
  asm volatile("s_waitcnt vmcnt(6)" ::: "memory");
  __builtin_amdgcn_s_barrier();
  __builtin_amdgcn_sched_barrier(0);

  for (int tile = 0; tile < NT; ++tile) {
#pragma unroll
    for (int m = 0; m < 4; ++m)
#pragma unroll
      for (int n = 0; n < 4; ++n) acc[m][n] = f32x4{0.f, 0.f, 0.f, 0.f};

    const bf16_t* nB0 = pB0 + 256 * 768;
    const bf16_t* nB1 = pB1 + 256 * 768;

    for (int t = 0; t < 21; ++t) ph(t, pB0, pB1, t + 3, ic<6>{}, ic<1>{});
    if (tile < NT - 1) {
      ph(21, nB0, nB1, 0, ic<6>{}, ic<1>{});   // stage next tile kt0 -> slot 0
      ph(22, nB0, nB1, 1, ic<6>{}, ic<1>{});   // kt1 -> slot 1
      ph(23, nB0, nB1, 2, ic<6>{}, ic<1>{});   // kt2 -> slot 2
    } else {
      ph(21, nB0, nB1, 0, ic<3>{}, ic<0>{});   // drain
      ph(22, nB0, nB1, 1, ic<0>{}, ic<0>{});
      ph(23, nB0, nB1, 2, ic<-1>{}, ic<0>{});
    }

    // ---- epilogue for this tile (no LDS; overlaps next tile's prefetch)
    const int bx = tile;
    const int colb = bx * 256 + wc * 64;
    float bcol[4];
#pragma unroll
    for (int n = 0; n < 4; ++n) bcol[n] = bias[colb + n * 16 + lq];

    if (MODE == 0) {
      const int sec = bx / 3;             // 0=Q, 1=K, 2=V  (NT==9, 768%256==0)
      bf16_t* base = sec == 0 ? Cq : (sec == 1 ? Ck : Cv);
      const int coll = colb - sec * 768;
      if (sec < 2) {
        // RoPE: 32-col chunk pair (n0,n1) = axis a0, (n2,n3) = axis a1.
        const int a0 = (colb % 96) >> 5;
        const int a1 = ((colb + 32) % 96) >> 5;
        const float fr = exp2f(-0.41524101186f * (float)lq);  // 100^(-lq/16)
#pragma unroll
        for (int m = 0; m < 4; ++m) {
          const int rowb = by * 128 + wr * 64 + m * 16 + lk * 4;
#pragma unroll
          for (int r = 0; r < 4; ++r) {
            const int row = rowb + r;
            float s0, c0, s1, c1;
            __sincosf(posf[row * 3 + a0] * fr, &s0, &c0);
            __sincosf(posf[row * 3 + a1] * fr, &s1, &c1);
            const float x1 = acc[m][0][r] + bcol[0], x2 = acc[m][1][r] + bcol[1];
            const float y1 = acc[m][2][r] + bcol[2], y2 = acc[m][3][r] + bcol[3];
            acc[m][0][r] = x1 * c0 - x2 * s0;
            acc[m][1][r] = x1 * s0 + x2 * c0;
            acc[m][2][r] = y1 * c1 - y2 * s1;
            acc[m][3][r] = y1 * s1 + y2 * c1;
          }
#pragma unroll
          for (int n = 0; n < 4; ++n) {
            const int col = coll + n * 16 + lq;
#pragma unroll
            for (int r = 0; r < 4; ++r)
              base[(size_t)(rowb + r) * 768 + col] = (bf16_t)acc[m][n][r];
          }
        }
      } else {
#pragma unroll
        for (int m = 0; m < 4; ++m) {
          const int rowb = by * 128 + wr * 64 + m * 16 + lk * 4;
#pragma unroll
          for (int n = 0; n < 4; ++n) {
            const int col = coll + n * 16 + lq;
#pragma unroll
            for (int r = 0; r < 4; ++r)
              base[(size_t)(rowb + r) * 768 + col] = (bf16_t)(acc[m][n][r] + bcol[n]);
          }
        }
      }
    } else {
#pragma unroll
      for (int m = 0; m < 4; ++m) {
        const int rowb = by * 128 + wr * 64 + m * 16 + lk * 4;
        int ro[4];
#pragma unroll
        for (int r = 0; r < 4; ++r) ro[r] = order[rowb + r];
#pragma unroll
        for (int n = 0; n < 4; ++n) {
          const int col = colb + n * 16 + lq;
#pragma unroll
          for (int r = 0; r < 4; ++r)
            Cf[(size_t)ro[r] * 768 + col] = acc[m][n][r] + bcol[n];
        }
      }
    }

    pB0 = nB0;
    pB1 = nB1;
  }
}

// ---------------- pack: Kb/Vb (roped, row-major) -> MFMA-frag Kp/Vp ------------
__global__ __launch_bounds__(256) void pack_k(const bf16_t* __restrict__ Kb,
                                              const bf16_t* __restrict__ Vb,
                                              bf16_t* __restrict__ Kp,
                                              bf16_t* __restrict__ Vp) {
  __shared__ bf16_t VT[96 * 264];  // [feat][token], +8 pad: conflict-free both ways
  const int h = blockIdx.x, p = blockIdx.y;
  const int tid = threadIdx.x;
  const int tok0 = p * 256;
  const size_t phb = (size_t)(p * 8 + h) * 24576;

  // K: 16B-chunk permutation
#pragma unroll
  for (int i = 0; i < 12; ++i) {
    const int c = i * 256 + tid;
    const int fi = c >> 6, ln = c & 63;
    const int nt = fi / 3, a = fi - nt * 3;
    const int tok = nt * 16 + (ln & 15), feat = a * 32 + (ln >> 4) * 8;
    *(bf16x8*)(Kp + phb + (size_t)c * 8) =
        *(const bf16x8*)(Kb + (size_t)(tok0 + tok) * 768 + h * 96 + feat);
  }

  // V: stage transposed into LDS (u16 writes: lanes consecutive -> conflict-free)
  {
    const bf16_t* vrow = Vb + (size_t)(tok0 + tid) * 768 + h * 96;
#pragma unroll
    for (int d0 = 0; d0 < 96; d0 += 8) {
      bf16x8 v = *(const bf16x8*)(vrow + d0);
#pragma unroll
      for (int i = 0; i < 8; ++i) VT[(d0 + i) * 264 + tid] = v[i];
    }
  }
  __syncthreads();
  // V: frag chunks = 8 consecutive tokens @ fixed feat = b128 from VT, coalesced out
#pragma unroll
  for (int i = 0; i < 12; ++i) {
    const int c = i * 256 + tid;
    const int fi = c >> 6, ln = c & 63;  // fi = dt*8+kc
    const int d = (fi >> 3) * 16 + (ln & 15);
    const int tb = (fi & 7) * 32 + (ln >> 4) * 8;
    *(bf16x8*)(Vp + phb + (size_t)c * 8) = *(const bf16x8*)(VT + d * 264 + tb);
  }
}

// ---------------- windowed attention (v4: LDS-staged K then V) -----------------
__global__ __launch_bounds__(256) void attn_k(bf16_t* QO,   // Q in, O out (same buffer)
                                              const bf16_t* __restrict__ Kp,
                                              const bf16_t* __restrict__ Vp) {
  __shared__ bf16_t KV[24576];     // 48KB: K frags, then V frags
  __shared__ bf16_t Pb[4][2048];   // 16KB: per-wave swizzled 16x128 P half
  const int bid = blockIdx.x;
  const int chunk = bid & 3;
  const int ph = bid >> 2;
  const int h = ph & 7, p = ph >> 3;
  const int tid = threadIdx.x, lane = tid & 63, wave = tid >> 6;
  const int lq = lane & 15, lk = lane >> 4;
  const int tok0 = p * 256;
  const int qrow0 = chunk * 64 + wave * 16;
  const bf16_t* Kps = Kp + (size_t)ph * 24576;
  const bf16_t* Vps = Vp + (size_t)ph * 24576;
  const float scale = 0.10206207262f;  // 96^-0.5

  // ---- stage K frags (48KB) async; Q frag loads overlap
#pragma unroll
  for (int i = 0; i < 12; ++i)
    gload_lds16(Kps + i * 2048 + tid * 8, KV + i * 2048 + tid * 8);
  bf16x8 aq[3];
  {
    const bf16_t* qb = QO + (size_t)(tok0 + qrow0 + lq) * 768 + h * 96 + lk * 8;
#pragma unroll
    for (int kc = 0; kc < 3; ++kc) aq[kc] = *(const bf16x8*)(qb + kc * 32);
  }
  __syncthreads();

  // ---- S = Q.K^T from LDS
  f32x4 sacc[16];
#pragma unroll
  for (int nt = 0; nt < 16; ++nt) {
    f32x4 acc = {0.f, 0.f, 0.f, 0.f};
#pragma unroll
    for (int kc = 0; kc < 3; ++kc) {
      bf16x8 bk = *(const bf16x8*)(KV + (size_t)((nt * 3 + kc) * 64 + lane) * 8);
      acc = __builtin_amdgcn_mfma_f32_16x16x32_bf16(aq[kc], bk, acc, 0, 0, 0);
    }
    sacc[nt] = acc;
  }
  __syncthreads();   // all waves done reading K from LDS

  // ---- restage V frags into same LDS (async; overlaps softmax VALU)
#pragma unroll
  for (int i = 0; i < 12; ++i)
    gload_lds16(Vps + i * 2048 + tid * 8, KV + i * 2048 + tid * 8);

  // ---- softmax (rows in C-layout: row = lk*4+r, col = nt*16+lq)
  float linv[4];
#pragma unroll
  for (int r = 0; r < 4; ++r) {
    float mx = -1e30f;
#pragma unroll
    for (int nt = 0; nt < 16; ++nt) mx = fmaxf(mx, sacc[nt][r]);
    mx = fmaxf(mx, __shfl_xor(mx, 1));
    mx = fmaxf(mx, __shfl_xor(mx, 2));
    mx = fmaxf(mx, __shfl_xor(mx, 4));
    mx = fmaxf(mx, __shfl_xor(mx, 8));
    mx *= scale;
    float l = 0.f;
#pragma unroll
    for (int nt = 0; nt < 16; ++nt) {
      float e = __expf(sacc[nt][r] * scale - mx);
      sacc[nt][r] = e;
      l += e;
    }
    l += __shfl_xor(l, 1);
    l += __shfl_xor(l, 2);
    l += __shfl_xor(l, 4);
    l += __shfl_xor(l, 8);
    linv[r] = 1.f / l;
  }
  __syncthreads();   // V staged

  // ---- PV in two 128-token halves through private swizzled P buffer.
  bf16_t* pw = &Pb[wave][0];
  f32x4 oacc[6] = {};
#pragma unroll
  for (int hf = 0; hf < 2; ++hf) {
#pragma unroll
    for (int ntl = 0; ntl < 8; ++ntl) {
      const int nt = hf * 8 + ntl;
      const int chk = ntl * 2 + (lq >> 3);
#pragma unroll
      for (int r = 0; r < 4; ++r) {
        const int row = lk * 4 + r;
        const int phys = chk ^ (row & 7);
        pw[row * 128 + phys * 8 + (lq & 7)] = (bf16_t)sacc[nt][r];
      }
    }
#pragma unroll
    for (int kcl = 0; kcl < 4; ++kcl) {
      const int physr = (kcl * 4 + lk) ^ (lq & 7);
      bf16x8 pf = *(const bf16x8*)(pw + lq * 128 + physr * 8);
      const int kc = hf * 4 + kcl;
#pragma unroll
      for (int dt = 0; dt < 6; ++dt) {
        bf16x8 vb = *(const bf16x8*)(KV + (size_t)((dt * 8 + kc) * 64 + lane) * 8);
        oacc[dt] = __builtin_amdgcn_mfma_f32_16x16x32_bf16(pf, vb, oacc[dt], 0, 0, 0);
      }
    }
  }

  // ---- write O over Q (same rows this wave read; safe in-place)
#pragma unroll
  for (int dt = 0; dt < 6; ++dt) {
#pragma unroll
    for (int r = 0; r < 4; ++r) {
      const int row = tok0 + qrow0 + lk * 4 + r;
      QO[(size_t)row * 768 + h * 96 + dt * 16 + lq] = (bf16_t)(oacc[dt][r] * linv[r]);
    }
  }
}

extern "C" void kernel_launch(void* const* d_in, const int* in_sizes, int n_in,
                              void* d_out, int out_size, void* d_ws, size_t ws_size,
                              hipStream_t stream) {
  const float* feat       = (const float*)d_in[0];
  const int*   grid_coord = (const int*)d_in[1];
  const int*   order      = (const int*)d_in[2];
  // d_in[3] = inverse (unused: scatter-by-order is equivalent)
  const float* w_qkv      = (const float*)d_in[4];
  const float* b_qkv      = (const float*)d_in[5];
  const float* w_proj     = (const float*)d_in[6];
  const float* b_proj     = (const float*)d_in[7];
  float* out = (float*)d_out;

  char* ws = (char*)d_ws;
  bf16_t* Bt1   = (bf16_t*)(ws);                 // 2304x768  bf16
  bf16_t* Bt2   = (bf16_t*)(ws + 3538944);       // 768x768   bf16
  bf16_t* featp = (bf16_t*)(ws + 4718592);       // 32768x768 bf16
  bf16_t* Kp    = featp;                         // featp dead after gemm1; reuse
  bf16_t* Qb    = (bf16_t*)(ws + 55050240);      // 32768x768 bf16
  bf16_t* Kb    = (bf16_t*)(ws + 105381888);     // 32768x768 bf16
  bf16_t* Vb    = (bf16_t*)(ws + 155713536);     // 32768x768 bf16
  bf16_t* Vp    = (bf16_t*)(ws + 206045184);     // 1024x24576 bf16
  float*  posf  = (float*)(ws + 206045184);      // 32768x3 fp32 — aliases Vp
  // posf lives gather->gemm1; Vp lives pack->attn; lifetimes are disjoint.

  static bool attr_set = false;
  if (!attr_set) {
    (void)hipFuncSetAttribute((const void*)gemm128_k<0, 9>,
                              hipFuncAttributeMaxDynamicSharedMemorySize, 98304);
    (void)hipFuncSetAttribute((const void*)gemm128_k<1, 3>,
                              hipFuncAttributeMaxDynamicSharedMemorySize, 98304);
    attr_set = true;
  }

  transpose_cast_k<<<dim3(36, 12), 256, 0, stream>>>(w_qkv, Bt1, 768, 2304);
  transpose_cast_k<<<dim3(12, 12), 256, 0, stream>>>(w_proj, Bt2, 768, 768);
  gather_cast_k<<<24576, 256, 0, stream>>>(feat, order, grid_coord, featp, posf);
  gemm128_k<0, 9><<<256, 512, 98304, stream>>>(featp, Bt1, b_qkv, Qb, Kb, Vb,
                                               nullptr, nullptr, posf);
  pack_k<<<dim3(8, 128), 256, 0, stream>>>(Kb, Vb, Kp, Vp);
  attn_k<<<4096, 256, 0, stream>>>(Qb, Kp, Vp);
  gemm128_k<1, 3><<<256, 512, 98304, stream>>>(Qb, Bt2, b_proj, nullptr, nullptr,
                                               nullptr, out, order, nullptr);
}

// Round 3
// 483.703 us; speedup vs baseline: 1.1750x; 1.1750x over previous
//
#include <hip/hip_runtime.h>
#include <hip/hip_bf16.h>
#include <stdint.h>

typedef __bf16 bf16_t;
typedef __bf16 bf16x8 __attribute__((ext_vector_type(8)));
typedef __bf16 bf16x4 __attribute__((ext_vector_type(4)));
typedef float f32x4 __attribute__((ext_vector_type(4)));

template <int V> struct ic { static constexpr int value = V; };

// async global->LDS, 16B per lane. LDS dest must be wave-uniform base + lane*16;
// the GLOBAL source is per-lane (used below to fold the frag-pack permutation
// into the staging itself).
__device__ __forceinline__ void gload_lds16(const bf16_t* g, bf16_t* l) {
  __builtin_amdgcn_global_load_lds((const __attribute__((address_space(1))) void*)g,
                                   (__attribute__((address_space(3))) void*)l, 16, 0, 0);
}

// ---------------- fp32 W[k][m] -> bf16 Bt[m][k] (tiled transpose + cast) --------
__global__ __launch_bounds__(256) void transpose_cast_k(const float* __restrict__ W,
                                                        bf16_t* __restrict__ Bt,
                                                        int KDin, int MDin) {
  __shared__ float tile[64][65];
  const int bm = blockIdx.x, bk = blockIdx.y;
  const int c = threadIdx.x & 63, r0 = threadIdx.x >> 6;
#pragma unroll
  for (int rr = 0; rr < 16; ++rr) {
    int row = rr * 4 + r0;
    tile[row][c] = W[(size_t)(bk * 64 + row) * MDin + bm * 64 + c];
  }
  __syncthreads();
#pragma unroll
  for (int rr = 0; rr < 16; ++rr) {
    int mo = rr * 4 + r0;
    Bt[(size_t)(bm * 64 + mo) * KDin + bk * 64 + c] = (bf16_t)tile[c][mo];
  }
}

// ---------------- feat[order[j]] -> bf16 featp[j]; also emit posf[j][3] --------
__global__ __launch_bounds__(256) void gather_cast_k(const float* __restrict__ feat,
                                                     const int* __restrict__ order,
                                                     const int* __restrict__ grid_coord,
                                                     bf16_t* __restrict__ featp,
                                                     float* __restrict__ posf) {
  const int id = blockIdx.x * 256 + threadIdx.x;  // 32768*192 total
  const int j = id / 192;
  const int c = (id % 192) * 4;
  const int g = order[j];
  const float4 v = *(const float4*)(feat + (size_t)g * 768 + c);
  bf16x4 o;
  o[0] = (bf16_t)v.x; o[1] = (bf16_t)v.y; o[2] = (bf16_t)v.z; o[3] = (bf16_t)v.w;
  *(bf16x4*)(featp + (size_t)j * 768 + c) = o;
  if (c == 0) {
    posf[j * 3 + 0] = (float)grid_coord[g * 3 + 0];
    posf[j * 3 + 1] = (float)grid_coord[g * 3 + 1];
    posf[j * 3 + 2] = (float)grid_coord[g * 3 + 2];
  }
}

// ---------------- 256x256 deep-pipelined GEMM: C[j][m] = A[j][:].Bt[m][:]+bias --
// A [M][768] bf16, Bt [N][768] bf16, K=768 = 24 tiles of BK=32.
// 8 waves (2Mx4N), per-wave 128x64 out. LDS = ring of 4 K-tile buffers
// (A:16KB + B:16KB each) = 128KB dynamic. Per K-tile: 2 phases x 16 MFMA.
// Stage depth: tile t+3 staged during group t (A at phase1, B at phase2);
// counted vmcnt(8) once per group (epilogue drains 8->4->0), raw s_barriers,
// setprio around MFMA clusters. LDS slot-XOR swizzle (slot ^= (row>>1)&3)
// applied via pre-swizzled GLOBAL source + linear global_load_lds dest, and
// the same XOR on the ds_read side.
// MODE 0: bf16 stores into Cq/Ck (fused RoPE) and TRANSPOSED V into
//         Cv = Vt[feat][token] (so attn can stage V-frags as contiguous 16B).
// MODE 1: fp32 scatter Cf[order[j]][768].
template <int MODE, int NBX>
__global__ __launch_bounds__(512, 2) void gemm256_k(const bf16_t* __restrict__ A,
                                                    const bf16_t* __restrict__ Bt,
                                                    const float* __restrict__ bias,
                                                    bf16_t* __restrict__ Cq,
                                                    bf16_t* __restrict__ Ck,
                                                    bf16_t* __restrict__ Cv,
                                                    float* __restrict__ Cf,
                                                    const int* __restrict__ order,
                                                    const float* __restrict__ posf) {
  extern __shared__ bf16_t sm[];          // [4][8192] A bufs, then [4][8192] B bufs
  bf16_t* ldsA = sm;
  bf16_t* ldsB = sm + 4 * 8192;

  const int tid = threadIdx.x;
  const int lane = tid & 63, wave = tid >> 6;
  const int wr = wave >> 2, wc = wave & 3;  // 2 x 4 wave grid
  const int lq = lane & 15, lk = lane >> 4;

  // bijective XCD swizzle; within an XCD chunk: by-major sweep of all NBX bx
  // (A panels L2-hit across the NBX consecutive blocks; B panels stay warm).
  const int bid = blockIdx.x;
  const int cpx = gridDim.x >> 3;         // gridDim.x % 8 == 0
  const int rm = (bid & 7) * cpx + (bid >> 3);
  const int by = rm / NBX, bx = rm % NBX;

  // ---- staging geometry: 16KB panel = 1024 16B-units; unit o = r*4 + phys,
  // phys = logical_slot ^ ((r>>1)&3).  Thread stages units {tid, tid+512}.
  const int o0 = tid, o1 = tid + 512;
  const int r0s = o0 >> 2, ls0 = (o0 & 3) ^ ((r0s >> 1) & 3);
  const int r1s = o1 >> 2, ls1 = (o1 & 3) ^ ((r1s >> 1) & 3);
  const bf16_t* pA0 = A + (size_t)(by * 256 + r0s) * 768 + ls0 * 8;
  const bf16_t* pA1 = A + (size_t)(by * 256 + r1s) * 768 + ls1 * 8;
  const bf16_t* pB0 = Bt + (size_t)(bx * 256 + r0s) * 768 + ls0 * 8;
  const bf16_t* pB1 = Bt + (size_t)(bx * 256 + r1s) * 768 + ls1 * 8;

  auto stageA = [&](int kt) {
    bf16_t* d = ldsA + ((kt & 3) << 13);
    gload_lds16(pA0 + kt * 32, d + o0 * 8);
    gload_lds16(pA1 + kt * 32, d + o1 * 8);
  };
  auto stageB = [&](int kt) {
    bf16_t* d = ldsB + ((kt & 3) << 13);
    gload_lds16(pB0 + kt * 32, d + o0 * 8);
    gload_lds16(pB1 + kt * 32, d + o1 * 8);
  };

  // ds_read slot for this lane (row = 16-aligned base + lq, so (row>>1)&3 = (lq>>1)&3)
  const int pslot = lk ^ ((lq >> 1) & 3);

  f32x4 acc[8][4] = {};

  // ---- prologue: stage tiles 0,1,2; wait for tile 0 (oldest 4 of 12 loads)
  stageA(0); stageB(0); stageA(1); stageB(1); stageA(2); stageB(2);
  asm volatile("s_waitcnt vmcnt(8)" ::: "memory");
  __builtin_amdgcn_s_barrier();
  __builtin_amdgcn_sched_barrier(0);

  auto group = [&](int t, auto VMC, auto STGC) {
    constexpr int VM = decltype(VMC)::value;
    constexpr bool STG = decltype(STGC)::value;
    const bf16_t* Ab = ldsA + ((t & 3) << 13);
    const bf16_t* Bb = ldsB + ((t & 3) << 13);
    bf16x8 af[4], bfr[4];
    // ---- phase 1: mh = 0 ----
#pragma unroll
    for (int m = 0; m < 4; ++m)
      af[m] = *(const bf16x8*)(Ab + (wr * 128 + m * 16 + lq) * 32 + pslot * 8);
#pragma unroll
    for (int n = 0; n < 4; ++n)
      bfr[n] = *(const bf16x8*)(Bb + (wc * 64 + n * 16 + lq) * 32 + pslot * 8);
    if constexpr (STG) stageA(t + 3);
    __builtin_amdgcn_s_barrier();
    asm volatile("s_waitcnt lgkmcnt(0)" ::: "memory");
    __builtin_amdgcn_s_setprio(1);
#pragma unroll
    for (int n = 0; n < 4; ++n)
#pragma unroll
      for (int m = 0; m < 4; ++m)
        acc[m][n] = __builtin_amdgcn_mfma_f32_16x16x32_bf16(af[m], bfr[n], acc[m][n], 0, 0, 0);
    __builtin_amdgcn_s_setprio(0);
    __builtin_amdgcn_s_barrier();
    // ---- phase 2: mh = 1 (reuse bfr) ----
#pragma unroll
    for (int m = 0; m < 4; ++m)
      af[m] = *(const bf16x8*)(Ab + (wr * 128 + 64 + m * 16 + lq) * 32 + pslot * 8);
    if constexpr (STG) stageB(t + 3);
    if constexpr (VM == 8) asm volatile("s_waitcnt vmcnt(8)" ::: "memory");
    else if constexpr (VM == 4) asm volatile("s_waitcnt vmcnt(4)" ::: "memory");
    else if constexpr (VM == 0) asm volatile("s_waitcnt vmcnt(0)" ::: "memory");
    __builtin_amdgcn_s_barrier();
    asm volatile("s_waitcnt lgkmcnt(0)" ::: "memory");
    __builtin_amdgcn_s_setprio(1);
#pragma unroll
    for (int n = 0; n < 4; ++n)
#pragma unroll
      for (int m = 0; m < 4; ++m)
        acc[4 + m][n] = __builtin_amdgcn_mfma_f32_16x16x32_bf16(af[m], bfr[n], acc[4 + m][n], 0, 0, 0);
    __builtin_amdgcn_s_setprio(0);
    __builtin_amdgcn_s_barrier();
    __builtin_amdgcn_sched_barrier(0);   // keep next group's ds_reads below this point
  };

  for (int t = 0; t < 21; ++t) group(t, ic<8>{}, ic<1>{});
  group(21, ic<4>{}, ic<0>{});
  group(22, ic<0>{}, ic<0>{});
  group(23, ic<-1>{}, ic<0>{});

  // ---- epilogue ----
  const int colb = bx * 256 + wc * 64;
  float bcol[4];
#pragma unroll
  for (int n = 0; n < 4; ++n) bcol[n] = bias[colb + n * 16 + lq];

  if (MODE == 0) {
    const int sec = bx / 3;               // 0=Q, 1=K, 2=V  (NBX==9, 768%256==0)
    const int coll = colb - sec * 768;
    if (sec < 2) {
      bf16_t* base = sec == 0 ? Cq : Ck;
      // RoPE: 32-col chunk pair (n0,n1) = axis a0, (n2,n3) = axis a1.
      const int a0 = (colb % 96) >> 5;
      const int a1 = ((colb + 32) % 96) >> 5;
      const float fr = exp2f(-0.41524101186f * (float)lq);  // 100^(-lq/16)
#pragma unroll
      for (int m = 0; m < 8; ++m) {
        const int rowb = by * 256 + wr * 128 + m * 16 + lk * 4;
#pragma unroll
        for (int r = 0; r < 4; ++r) {
          const int row = rowb + r;
          float s0, c0, s1, c1;
          __sincosf(posf[row * 3 + a0] * fr, &s0, &c0);
          __sincosf(posf[row * 3 + a1] * fr, &s1, &c1);
          const float x1 = acc[m][0][r] + bcol[0], x2 = acc[m][1][r] + bcol[1];
          const float y1 = acc[m][2][r] + bcol[2], y2 = acc[m][3][r] + bcol[3];
          acc[m][0][r] = x1 * c0 - x2 * s0;
          acc[m][1][r] = x1 * s0 + x2 * c0;
          acc[m][2][r] = y1 * c1 - y2 * s1;
          acc[m][3][r] = y1 * s1 + y2 * c1;
        }
#pragma unroll
        for (int n = 0; n < 4; ++n) {
          const int col = coll + n * 16 + lq;
#pragma unroll
          for (int r = 0; r < 4; ++r)
            base[(size_t)(rowb + r) * 768 + col] = (bf16_t)acc[m][n][r];
        }
      }
    } else {
      // V: store TRANSPOSED -> Cv = Vt[feat][token] (32768 tokens per row).
      // 4 consecutive tokens per thread -> one bf16x4 (8B) store.
#pragma unroll
      for (int m = 0; m < 8; ++m) {
        const int rowb = by * 256 + wr * 128 + m * 16 + lk * 4;
#pragma unroll
        for (int n = 0; n < 4; ++n) {
          const int col = coll + n * 16 + lq;
          bf16x4 o;
#pragma unroll
          for (int r = 0; r < 4; ++r) o[r] = (bf16_t)(acc[m][n][r] + bcol[n]);
          *(bf16x4*)(Cv + (size_t)col * 32768 + rowb) = o;
        }
      }
    }
  } else {
#pragma unroll
    for (int m = 0; m < 8; ++m) {
      const int rowb = by * 256 + wr * 128 + m * 16 + lk * 4;
      int ro[4];
#pragma unroll
      for (int r = 0; r < 4; ++r) ro[r] = order[rowb + r];
#pragma unroll
      for (int n = 0; n < 4; ++n) {
        const int col = colb + n * 16 + lq;
#pragma unroll
        for (int r = 0; r < 4; ++r)
          Cf[(size_t)ro[r] * 768 + col] = acc[m][n][r] + bcol[n];
      }
    }
  }
}

// ---------------- windowed attention (direct-stage from Kb / Vt) ---------------
// grid = ph*4 chunks; block = 4 waves, each owns 16 q-rows of one (p,h).
// K-frags staged straight from row-major Kb via per-lane permuted global
// addresses (16B chunks are contiguous in Kb); V-frags staged straight from
// the transposed Vt[feat][token] (16B chunks contiguous there).  The former
// pack_k kernel is gone entirely.
__global__ __launch_bounds__(256) void attn_k(bf16_t* QO,   // Q in, O out (same buffer)
                                              const bf16_t* __restrict__ Kb,
                                              const bf16_t* __restrict__ Vt) {
  __shared__ bf16_t KV[24576];     // 48KB: K frags, then V frags
  __shared__ bf16_t Pb[4][2048];   // 16KB: per-wave swizzled 16x128 P half
  const int bid = blockIdx.x;
  const int chunk = bid & 3;
  const int ph = bid >> 2;
  const int h = ph & 7, p = ph >> 3;
  const int tid = threadIdx.x, lane = tid & 63, wave = tid >> 6;
  const int lq = lane & 15, lk = lane >> 4;
  const int tok0 = p * 256;
  const int qrow0 = chunk * 64 + wave * 16;
  const float scale = 0.10206207262f;  // 96^-0.5

  // ---- stage K frags (48KB) async, straight from Kb; Q frag loads overlap.
  // chunk c = i*256 + tid; fi = c>>6 = i*4 + wave; ln = lane.
  // frag chunk (fi,ln) = Kb[tok0 + nt*16 + (ln&15)][h*96 + a*32 + (ln>>4)*8 ..+7],
  // nt = fi/3, a = fi%3  (identical mapping to the old pack_k K permutation).
#pragma unroll
  for (int i = 0; i < 12; ++i) {
    const int fi = i * 4 + wave;
    const int nt = fi / 3, a = fi - nt * 3;
    const bf16_t* src = Kb + (size_t)(tok0 + nt * 16 + (lane & 15)) * 768 +
                        h * 96 + a * 32 + (lane >> 4) * 8;
    gload_lds16(src, KV + i * 2048 + tid * 8);
  }
  bf16x8 aq[3];
  {
    const bf16_t* qb = QO + (size_t)(tok0 + qrow0 + lq) * 768 + h * 96 + lk * 8;
#pragma unroll
    for (int kc = 0; kc < 3; ++kc) aq[kc] = *(const bf16x8*)(qb + kc * 32);
  }
  __syncthreads();

  // ---- S = Q.K^T from LDS
  f32x4 sacc[16];
#pragma unroll
  for (int nt = 0; nt < 16; ++nt) {
    f32x4 acc = {0.f, 0.f, 0.f, 0.f};
#pragma unroll
    for (int kc = 0; kc < 3; ++kc) {
      bf16x8 bk = *(const bf16x8*)(KV + (size_t)((nt * 3 + kc) * 64 + lane) * 8);
      acc = __builtin_amdgcn_mfma_f32_16x16x32_bf16(aq[kc], bk, acc, 0, 0, 0);
    }
    sacc[nt] = acc;
  }
  __syncthreads();   // all waves done reading K from LDS

  // ---- restage V frags into same LDS (async; overlaps softmax VALU).
  // frag chunk (fi,ln) = V[tok0 + tb .. +7][h*96 + d]  (8 consecutive tokens at
  // fixed feat) = 16 contiguous bytes of Vt[h*96+d][tok0+tb];
  // d = (fi>>3)*16 + (ln&15), tb = (fi&7)*32 + (ln>>4)*8.
#pragma unroll
  for (int i = 0; i < 12; ++i) {
    const int fi = i * 4 + wave;
    const int d = (fi >> 3) * 16 + (lane & 15);
    const int tb = (fi & 7) * 32 + (lane >> 4) * 8;
    const bf16_t* src = Vt + (size_t)(h * 96 + d) * 32768 + tok0 + tb;
    gload_lds16(src, KV + i * 2048 + tid * 8);
  }

  // ---- softmax (rows in C-layout: row = lk*4+r, col = nt*16+lq)
  float linv[4];
#pragma unroll
  for (int r = 0; r < 4; ++r) {
    float mx = -1e30f;
#pragma unroll
    for (int nt = 0; nt < 16; ++nt) mx = fmaxf(mx, sacc[nt][r]);
    mx = fmaxf(mx, __shfl_xor(mx, 1));
    mx = fmaxf(mx, __shfl_xor(mx, 2));
    mx = fmaxf(mx, __shfl_xor(mx, 4));
    mx = fmaxf(mx, __shfl_xor(mx, 8));
    mx *= scale;
    float l = 0.f;
#pragma unroll
    for (int nt = 0; nt < 16; ++nt) {
      float e = __expf(sacc[nt][r] * scale - mx);
      sacc[nt][r] = e;
      l += e;
    }
    l += __shfl_xor(l, 1);
    l += __shfl_xor(l, 2);
    l += __shfl_xor(l, 4);
    l += __shfl_xor(l, 8);
    linv[r] = 1.f / l;
  }
  __syncthreads();   // V staged

  // ---- PV in two 128-token halves through private swizzled P buffer.
  // Same-wave DS ops are in-order, so no barrier needed around Pb.
  bf16_t* pw = &Pb[wave][0];
  f32x4 oacc[6] = {};
#pragma unroll
  for (int hf = 0; hf < 2; ++hf) {
#pragma unroll
    for (int ntl = 0; ntl < 8; ++ntl) {
      const int nt = hf * 8 + ntl;
      const int chk = ntl * 2 + (lq >> 3);
#pragma unroll
      for (int r = 0; r < 4; ++r) {
        const int row = lk * 4 + r;
        const int phys = chk ^ (row & 7);
        pw[row * 128 + phys * 8 + (lq & 7)] = (bf16_t)sacc[nt][r];
      }
    }
#pragma unroll
    for (int kcl = 0; kcl < 4; ++kcl) {
      const int physr = (kcl * 4 + lk) ^ (lq & 7);
      bf16x8 pf = *(const bf16x8*)(pw + lq * 128 + physr * 8);
      const int kc = hf * 4 + kcl;
#pragma unroll
      for (int dt = 0; dt < 6; ++dt) {
        bf16x8 vb = *(const bf16x8*)(KV + (size_t)((dt * 8 + kc) * 64 + lane) * 8);
        oacc[dt] = __builtin_amdgcn_mfma_f32_16x16x32_bf16(pf, vb, oacc[dt], 0, 0, 0);
      }
    }
  }

  // ---- write O over Q (same rows this wave read; safe in-place)
#pragma unroll
  for (int dt = 0; dt < 6; ++dt) {
#pragma unroll
    for (int r = 0; r < 4; ++r) {
      const int row = tok0 + qrow0 + lk * 4 + r;
      QO[(size_t)row * 768 + h * 96 + dt * 16 + lq] = (bf16_t)(oacc[dt][r] * linv[r]);
    }
  }
}

extern "C" void kernel_launch(void* const* d_in, const int* in_sizes, int n_in,
                              void* d_out, int out_size, void* d_ws, size_t ws_size,
                              hipStream_t stream) {
  const float* feat       = (const float*)d_in[0];
  const int*   grid_coord = (const int*)d_in[1];
  const int*   order      = (const int*)d_in[2];
  // d_in[3] = inverse (unused: scatter-by-order is equivalent)
  const float* w_qkv      = (const float*)d_in[4];
  const float* b_qkv      = (const float*)d_in[5];
  const float* w_proj     = (const float*)d_in[6];
  const float* b_proj     = (const float*)d_in[7];
  float* out = (float*)d_out;

  char* ws = (char*)d_ws;
  bf16_t* Bt1   = (bf16_t*)(ws);                 // 2304x768  bf16
  bf16_t* Bt2   = (bf16_t*)(ws + 3538944);       // 768x768   bf16
  bf16_t* featp = (bf16_t*)(ws + 4718592);       // 32768x768 bf16
  bf16_t* Qb    = (bf16_t*)(ws + 55050240);      // 32768x768 bf16
  bf16_t* Kb    = (bf16_t*)(ws + 105381888);     // 32768x768 bf16
  bf16_t* Vt    = (bf16_t*)(ws + 155713536);     // 768x32768 bf16 (V transposed)
  float*  posf  = (float*)(ws + 206045184);      // 32768x3 fp32

  static bool attr_set = false;
  if (!attr_set) {
    (void)hipFuncSetAttribute((const void*)gemm256_k<0, 9>,
                              hipFuncAttributeMaxDynamicSharedMemorySize, 131072);
    (void)hipFuncSetAttribute((const void*)gemm256_k<1, 3>,
                              hipFuncAttributeMaxDynamicSharedMemorySize, 131072);
    attr_set = true;
  }

  transpose_cast_k<<<dim3(36, 12), 256, 0, stream>>>(w_qkv, Bt1, 768, 2304);
  transpose_cast_k<<<dim3(12, 12), 256, 0, stream>>>(w_proj, Bt2, 768, 768);
  gather_cast_k<<<24576, 256, 0, stream>>>(feat, order, grid_coord, featp, posf);
  gemm256_k<0, 9><<<1152, 512, 131072, stream>>>(featp, Bt1, b_qkv, Qb, Kb, Vt,
                                                 nullptr, nullptr, posf);
  attn_k<<<4096, 256, 0, stream>>>(Qb, Kb, Vt);
  gemm256_k<1, 3><<<384, 512, 131072, stream>>>(Qb, Bt2, b_proj, nullptr, nullptr,
                                                nullptr, out, order, nullptr);
}